// Round 6
// baseline (256.036 us; speedup 1.0000x reference)
//
#include <hip/hip_runtime.h>
#include <math.h>

// SpikingSelfAttention on MI355X — event-driven, fused front-end.
// wconv -> [pool8 + QKV MFMA-GEMM fused, xp lives only in LDS] + spike(bf16,
// per-batch flags) -> attn (skipped for spike-free batches) -> out GEMM
// (bias fast path for spike-free batches) + BN + spike + repeat8.
// Correct for arbitrary inputs: flags derive from actual spike decisions;
// dense paths run whenever a batch has any spike; bf16 GEMMs carry an exact
// fp32 margin-fallback for near-threshold elements.

#define THRESH 2.0f
#define BN_EPS 1e-5f

typedef __attribute__((ext_vector_type(4))) float f32x4;
typedef __attribute__((ext_vector_type(8))) short bfrag;   // 8 bf16
typedef __attribute__((ext_vector_type(4))) short s16x4;   // 4 bf16

__device__ __forceinline__ short f2bf(float f) {  // RNE f32->bf16
  union { float f; unsigned u; } v; v.f = f;
  unsigned r = (v.u + 0x7FFFu + ((v.u >> 16) & 1u)) >> 16;
  return (short)r;
}
__device__ __forceinline__ float bf2f(short s) {
  union { unsigned u; float f; } v;
  v.u = ((unsigned)(unsigned short)s) << 16;
  return v.f;
}
__device__ __forceinline__ void gload16(const void* g, void* l) {
  __builtin_amdgcn_global_load_lds(
      (const __attribute__((address_space(1))) void*)g,
      (__attribute__((address_space(3))) void*)l, 16, 0, 0);
}

// ------- weights f32 -> bf16 (W_qkv, W_out) + zero the spike flags ----------
__global__ __launch_bounds__(256) void wconv_kernel(const float* __restrict__ wq,
                                                    const float* __restrict__ wo,
                                                    short* __restrict__ wqb,
                                                    short* __restrict__ wob,
                                                    int* __restrict__ flags) {
  int i = blockIdx.x * 256 + threadIdx.x;  // quads; n1=196608, n2=65536
  const int n1 = 1536 * 512 / 4;
  if (i < 32) flags[i] = 0;
  f32x4 v;
  s16x4 h;
  if (i < n1) {
    v = ((const f32x4*)wq)[i];
    h.x = f2bf(v.x); h.y = f2bf(v.y); h.z = f2bf(v.z); h.w = f2bf(v.w);
    ((s16x4*)wqb)[i] = h;
  } else {
    int j = i - n1;
    v = ((const f32x4*)wo)[j];
    h.x = f2bf(v.x); h.y = f2bf(v.y); h.z = f2bf(v.z); h.w = f2bf(v.w);
    ((s16x4*)wob)[j] = h;
  }
}

// ------- FUSED pool8 + QKV GEMM + spike + flags -----------------------------
// Block = (t-tile of 64 pooled t, batch b). Phase 1: pool x[b][:,t-slice]
// (1 MB HBM) into swizzled LDS tile xs[64 t][512 c] bf16 (xp never hits HBM).
// Phase 2: per wave, 384 o-rows x 64 t via MFMA; A-frags register-direct from
// L2-resident Wqb; B-frags from swizzled LDS. Spikes (bf16 0/1) to qkv;
// near-threshold exact fp32 fallback; per-batch anyspike flag.
__global__ __launch_bounds__(256) void pool_qkv_fused(
    const float* __restrict__ x, const short* __restrict__ Wqb,
    const float* __restrict__ Wf, short* __restrict__ qkv,
    int* __restrict__ flags) {
  const int b = blockIdx.y, t0 = blockIdx.x * 64;
  __shared__ short xs[64 * 512];  // 64 KiB, XOR-swizzled: elem[t][c^((t&7)<<3)]
  const int tid = threadIdx.x, lane = tid & 63, wave = tid >> 6;

  // ---- Phase 1: pool (each wave handles c = wave mod 4 residue class) ----
  {
    const int tl = lane;
    const float* xb = x + (size_t)b * 512 * 4096 + (size_t)t0 * 8;
#pragma unroll 4
    for (int ci = 0; ci < 128; ++ci) {
      const int c = wave + 4 * ci;
      const float* p = xb + (size_t)c * 4096 + tl * 8;
      float4 a = *(const float4*)p, d = *(const float4*)(p + 4);
      float v =
          (((a.x + a.y) + (a.z + a.w)) + ((d.x + d.y) + (d.z + d.w))) * 0.125f;
      xs[tl * 512 + (c ^ ((tl & 7) << 3))] = f2bf(v);
    }
  }
  __syncthreads();

  // ---- Phase 2: GEMM. wave covers o in [wave*384, wave*384+384) ----
  const int lrow = lane & 15, lk = (lane >> 4) * 8, lrg = (lane >> 4) * 4;
  short* OutB = qkv + (size_t)b * 1536 * 512 + t0;
  bool anyspike = false;

  for (int og = 0; og < 4; ++og) {  // 4 groups x 6 o-frags = 24 (384 o-rows)
    const int obase0 = wave * 384 + og * 96;
    f32x4 acc[6][4] = {};
#pragma unroll
    for (int kk = 0; kk < 512; kk += 32) {
      bfrag bf[4];
#pragma unroll
      for (int tf = 0; tf < 4; ++tf) {
        const int t = tf * 16 + lrow;
        bf[tf] = *(const bfrag*)(xs + t * 512 + ((kk + lk) ^ ((t & 7) << 3)));
      }
#pragma unroll
      for (int oi = 0; oi < 6; ++oi) {
        const int orow = obase0 + oi * 16 + lrow;
        bfrag af = *(const bfrag*)(Wqb + (size_t)orow * 512 + kk + lk);
#pragma unroll
        for (int tf = 0; tf < 4; ++tf)
          acc[oi][tf] = __builtin_amdgcn_mfma_f32_16x16x32_bf16(
              af, bf[tf], acc[oi][tf], 0, 0, 0);
      }
    }
    // epilogue for these 6 o-frags
#pragma unroll
    for (int oi = 0; oi < 6; ++oi) {
      unsigned fb = 0;
#pragma unroll
      for (int tf = 0; tf < 4; ++tf)
#pragma unroll
        for (int r = 0; r < 4; ++r) {
          const float v = acc[oi][tf][r];
          if (fabsf(v - THRESH) < 0.05f) fb |= 1u << (tf * 4 + r);
          else anyspike |= (v >= THRESH);
          const int orow = obase0 + oi * 16 + lrg + r;
          const int t = tf * 16 + lrow;
          OutB[(size_t)orow * 512 + t] = (v >= THRESH) ? (short)0x3F80 : (short)0;
        }
      if (__builtin_expect(fb != 0, 0)) {  // exact fp32 recompute, ~never
        for (int bit = 0; bit < 16; ++bit) {
          if (!((fb >> bit) & 1)) continue;
          const int tf = bit >> 2, r = bit & 3;
          const int orow = obase0 + oi * 16 + lrg + r;
          const int t = tf * 16 + lrow;
          const float* wrow = Wf + (size_t)orow * 512;
          const float* xcol =
              x + (size_t)b * 512 * 4096 + (size_t)(t0 + t) * 8;
          float s = 0.f;
          for (int c = 0; c < 512; ++c) {
            const float* xc = xcol + (size_t)c * 4096;
            float p = ((xc[0] + xc[1]) + (xc[2] + xc[3])) +
                      ((xc[4] + xc[5]) + (xc[6] + xc[7]));
            s += wrow[c] * (p * 0.125f);
          }
          const bool sp = (s >= THRESH);
          anyspike |= sp;
          OutB[(size_t)orow * 512 + t] = sp ? (short)0x3F80 : (short)0;
        }
      }
    }
  }
  unsigned long long bal = __ballot(anyspike);
  if (lane == 0 && bal != 0ull) atomicOr(&flags[b], 1);
}

// ------- attention (only for batches with spikes): M = V K^T (bf16 MFMA,
// exact on binary spikes), O = scale * M Q (fp32); emits attT f32 + attTb bf16.
__global__ __launch_bounds__(256) void attn_kernel(const short* __restrict__ qkvb,
                                                   float* __restrict__ attT,
                                                   short* __restrict__ attTb,
                                                   const int* __restrict__ flags) {
  const int b = blockIdx.z, h = blockIdx.y, th = blockIdx.x;  // th: t-half
  if (flags[b] == 0) return;  // no spikes in this batch -> attn output is 0
  const short* Q = qkvb + ((size_t)b * 1536 + h * 64) * 512;
  const short* K = qkvb + ((size_t)b * 1536 + 512 + h * 64) * 512;
  const short* V = qkvb + ((size_t)b * 1536 + 1024 + h * 64) * 512;

  __shared__ float Ms[64][65];  // Ms[e][d]
  __shared__ float Qs[64][65];  // Qs[e][tloc]
  __shared__ float Ts[64][65];  // Ts[tloc][d]

  const int tid = threadIdx.x, lane = tid & 63, wave = tid >> 6;
  const int lrow = lane & 15, lk = (lane >> 4) * 8, lrg = (lane >> 4) * 4;

  f32x4 mAcc[4] = {};
#pragma unroll 4
  for (int kk = 0; kk < 512; kk += 32) {
    bfrag a = *(const bfrag*)(V + (size_t)(wave * 16 + lrow) * 512 + kk + lk);
#pragma unroll
    for (int ni = 0; ni < 4; ++ni) {
      bfrag bb = *(const bfrag*)(K + (size_t)(ni * 16 + lrow) * 512 + kk + lk);
      mAcc[ni] = __builtin_amdgcn_mfma_f32_16x16x32_bf16(a, bb, mAcc[ni], 0, 0, 0);
    }
  }
#pragma unroll
  for (int ni = 0; ni < 4; ++ni)
#pragma unroll
    for (int r = 0; r < 4; ++r)
      Ms[ni * 16 + lrow][wave * 16 + lrg + r] = mAcc[ni][r];
  __syncthreads();

  const int tx = tid & 15, ty = tid >> 4;
  const int srow = tid >> 2, scseg = (tid & 3) * 16;
  for (int tt = th * 256; tt < th * 256 + 256; tt += 64) {
    {
      bfrag q0 = *(const bfrag*)(Q + (size_t)srow * 512 + tt + scseg);
      bfrag q1 = *(const bfrag*)(Q + (size_t)srow * 512 + tt + scseg + 8);
#pragma unroll
      for (int j = 0; j < 8; ++j) {
        Qs[srow][scseg + j] = bf2f(q0[j]);
        Qs[srow][scseg + 8 + j] = bf2f(q1[j]);
      }
    }
    __syncthreads();
    float acc[4][4] = {};
#pragma unroll
    for (int e = 0; e < 64; ++e) {
      float4 md = *reinterpret_cast<const float4*>(&Ms[e][ty << 2]);
      float4 qt = *reinterpret_cast<const float4*>(&Qs[e][tx << 2]);
      float mr[4] = {md.x, md.y, md.z, md.w};
      float qr[4] = {qt.x, qt.y, qt.z, qt.w};
#pragma unroll
      for (int i = 0; i < 4; ++i)
#pragma unroll
        for (int j = 0; j < 4; ++j) acc[i][j] += mr[i] * qr[j];
    }
#pragma unroll
    for (int i = 0; i < 4; ++i)
#pragma unroll
      for (int j = 0; j < 4; ++j)
        Ts[(tx << 2) + j][(ty << 2) + i] = acc[i][j] * 0.125f;
    __syncthreads();
    {
      float* dst = attT + ((size_t)b * 512 + tt + srow) * 512 + h * 64 + scseg;
      short* dstb = attTb + ((size_t)b * 512 + tt + srow) * 512 + h * 64 + scseg;
#pragma unroll
      for (int k = 0; k < 4; ++k) {
        float4 v = *reinterpret_cast<const float4*>(&Ts[srow][scseg + 4 * k]);
        *reinterpret_cast<float4*>(dst + 4 * k) = v;
        s16x4 hh;
        hh.x = f2bf(v.x); hh.y = f2bf(v.y); hh.z = f2bf(v.z); hh.w = f2bf(v.w);
        ((s16x4*)dstb)[k] = hh;
      }
    }
    __syncthreads();
  }
}

// ------- out GEMM + BN + spike + repeat8; bias fast path when batch spike-free
__global__ __launch_bounds__(256) void out_gemm_mfma(
    const short* __restrict__ Wob, const short* __restrict__ attTb,
    const float* __restrict__ Wf, const float* __restrict__ attT,
    const float* __restrict__ gamma, const float* __restrict__ beta,
    const float* __restrict__ mean, const float* __restrict__ var,
    float* __restrict__ out, const int* __restrict__ flags) {
  const int b = blockIdx.z, o0 = blockIdx.y * 128, t0 = blockIdx.x * 128;
  const int tid = threadIdx.x;

  if (flags[b] == 0) {
    // attn output is exactly 0 -> y = beta - mean*inv, uniform over t.
    __shared__ float sRow[128];
    if (tid < 128) {
      int o = o0 + tid;
      float inv = gamma[o] / sqrtf(var[o] + BN_EPS);
      float y = beta[o] - mean[o] * inv;
      sRow[tid] = (y >= THRESH) ? 1.0f : 0.0f;
    }
    __syncthreads();
    float* base = out + ((size_t)b * 512 + o0) * 4096 + (size_t)t0 * 8;
    for (int r = 0; r < 128; ++r) {
      float s = sRow[r];
      float4 sv = make_float4(s, s, s, s);
      reinterpret_cast<float4*>(base + (size_t)r * 4096)[tid] = sv;
    }
    return;
  }

  __shared__ __align__(16) short Asm[128 * 64];
  __shared__ __align__(16) short Bsm[128 * 64];
  const int lane = tid & 63, wave = tid >> 6;
  const int wr = (wave >> 1) * 64, wc = (wave & 1) * 64;
  const int lrow = lane & 15, lk = (lane >> 4) * 8;
  f32x4 acc[4][4] = {};
  const short* Ag = Wob + (size_t)o0 * 512;
  const short* Bg = attTb + ((size_t)b * 512 + t0) * 512;

  for (int k0 = 0; k0 < 512; k0 += 64) {
    __syncthreads();
#pragma unroll
    for (int i = 0; i < 4; ++i) {
      int idx = tid + 256 * i, row = idx >> 3, seg = idx & 7;
      gload16(Ag + (size_t)row * 512 + k0 + seg * 8, Asm + idx * 8);
    }
#pragma unroll
    for (int i = 0; i < 4; ++i) {
      int idx = tid + 256 * i, row = idx >> 3, seg = idx & 7;
      gload16(Bg + (size_t)row * 512 + k0 + seg * 8, Bsm + idx * 8);
    }
    __syncthreads();
#pragma unroll
    for (int kk = 0; kk < 64; kk += 32) {
      bfrag af[4], bfr[4];
#pragma unroll
      for (int mi = 0; mi < 4; ++mi)
        af[mi] = *(const bfrag*)(Asm + (wr + mi * 16 + lrow) * 64 + kk + lk);
#pragma unroll
      for (int ni = 0; ni < 4; ++ni)
        bfr[ni] = *(const bfrag*)(Bsm + (wc + ni * 16 + lrow) * 64 + kk + lk);
#pragma unroll
      for (int mi = 0; mi < 4; ++mi)
#pragma unroll
        for (int ni = 0; ni < 4; ++ni)
          acc[mi][ni] = __builtin_amdgcn_mfma_f32_16x16x32_bf16(
              af[mi], bfr[ni], acc[mi][ni], 0, 0, 0);
    }
  }

  const int lrg = (lane >> 4) * 4;
  unsigned long long fbm = 0;
#pragma unroll
  for (int mi = 0; mi < 4; ++mi)
#pragma unroll
    for (int r = 0; r < 4; ++r) {
      const int o = o0 + wr + mi * 16 + lrg + r;
      const float inv = gamma[o] / sqrtf(var[o] + BN_EPS);
      const float bias = beta[o] - mean[o] * inv;
#pragma unroll
      for (int ni = 0; ni < 4; ++ni) {
        int tt = t0 + wc + ni * 16 + lrow;
        float y = acc[mi][ni][r] * inv + bias;
        if (fabsf(y - THRESH) < 0.02f) fbm |= 1ull << (mi * 16 + ni * 4 + r);
        float s = (y >= THRESH) ? 1.0f : 0.0f;
        float4 sv = make_float4(s, s, s, s);
        float* dp = out + ((size_t)b * 512 + o) * 4096 + (size_t)tt * 8;
        ((float4*)dp)[0] = sv;
        ((float4*)dp)[1] = sv;
      }
    }
  if (__builtin_expect(fbm != 0, 0)) {  // exact fp32 recompute, ~never taken
    for (int bit = 0; bit < 64; ++bit) {
      if (!((fbm >> bit) & 1)) continue;
      int mi = bit >> 4, ni = (bit >> 2) & 3, r = bit & 3;
      int o = o0 + wr + mi * 16 + lrg + r;
      int tt = t0 + wc + ni * 16 + lrow;
      const float* wrow = Wf + (size_t)o * 512;
      const float* arow = attT + ((size_t)b * 512 + tt) * 512;
      float s = 0.f;
      for (int c = 0; c < 512; ++c) s += wrow[c] * arow[c];
      float inv = gamma[o] / sqrtf(var[o] + BN_EPS);
      float y = s * inv + (beta[o] - mean[o] * inv);
      float sp = (y >= THRESH) ? 1.0f : 0.0f;
      float4 sv = make_float4(sp, sp, sp, sp);
      float* dp = out + ((size_t)b * 512 + o) * 4096 + (size_t)tt * 8;
      ((float4*)dp)[0] = sv;
      ((float4*)dp)[1] = sv;
    }
  }
}

extern "C" void kernel_launch(void* const* d_in, const int* in_sizes, int n_in,
                              void* d_out, int out_size, void* d_ws, size_t ws_size,
                              hipStream_t stream) {
  (void)in_sizes; (void)n_in; (void)out_size; (void)ws_size;
  const float* x     = (const float*)d_in[0];
  const float* w_qkv = (const float*)d_in[1];
  const float* w_out = (const float*)d_in[2];
  const float* gamma = (const float*)d_in[3];
  const float* beta  = (const float*)d_in[4];
  const float* mean  = (const float*)d_in[5];
  const float* var   = (const float*)d_in[6];
  float* outp = (float*)d_out;

  // d_out-front scratch: qkvb bf16 (32,1536,512) in [0,48MB) — consumed by
  // attn BEFORE out_gemm writes d_out.
  // d_ws scratch (out_gemm inputs must NOT alias d_out):
  //   [0,32MB)   attT  f32  (32,512t,512c)
  //   [32,48MB)  attTb bf16 (32,512t,512c)
  //   [48MB)     Wqb bf16 (1536,512), [50MB) Wob bf16 (512,512),
  //   [51MB)     flags int[32]
  char* ob = (char*)d_out;
  char* wb = (char*)d_ws;
  short* qkvb = (short*)(ob);
  float* attT  = (float*)(wb);
  short* attTb = (short*)(wb + ((size_t)32 << 20));
  short* Wqb   = (short*)(wb + ((size_t)48 << 20));
  short* Wob   = (short*)(wb + ((size_t)50 << 20));
  int*   flags = (int*)(wb + ((size_t)51 << 20));

  wconv_kernel<<<1024, 256, 0, stream>>>(w_qkv, w_out, Wqb, Wob, flags);
  pool_qkv_fused<<<dim3(8, 32), 256, 0, stream>>>(x, Wqb, w_qkv, qkvb, flags);
  attn_kernel<<<dim3(2, 8, 32), 256, 0, stream>>>(qkvb, attT, attTb, flags);
  out_gemm_mfma<<<dim3(4, 4, 32), 256, 0, stream>>>(Wob, attTb, w_out, attT,
                                                    gamma, beta, mean, var,
                                                    outp, flags);
}